// Round 1
// baseline (321.692 us; speedup 1.0000x reference)
//
#include <hip/hip_runtime.h>
#include <hip/hip_fp16.h>

__device__ __forceinline__ float2 cadd(float2 a, float2 b) { return make_float2(a.x + b.x, a.y + b.y); }
__device__ __forceinline__ float2 csub(float2 a, float2 b) { return make_float2(a.x - b.x, a.y - b.y); }
__device__ __forceinline__ float2 cmul(float2 w, float2 z) {
    return make_float2(w.x * z.x - w.y * z.y, w.x * z.y + w.y * z.x);
}
__device__ __forceinline__ unsigned pk(float2 z) {
    __half2 h = __floats2half2_rn(z.x, z.y);
    return *reinterpret_cast<unsigned*>(&h);
}
__device__ __forceinline__ float2 upk(unsigned u) {
    __half2 h = *reinterpret_cast<__half2*>(&u);
    return __half22float2(h);
}

// compile-time bit reverse (folds inside #pragma unroll loops)
__host__ __device__ constexpr unsigned crev(unsigned x, int bits) {
    unsigned r = 0;
    for (int k = 0; k < bits; ++k) r |= ((x >> k) & 1u) << (bits - 1 - k);
    return r;
}

// Butterfly network (DIF, natural order, bit-reversed store at end):
//   stage t (0..22): pairs (i, i + 2^(22-t)); z'[i] = z[i] + w*z[i+D]; z'[i+D] = z[i] - w*z[i+D]
//   w = weight[ bitrev_t(i >> (23-t)) * 2^(22-t) ]
// Pass A: t=0..7 (bits 22..15), unchanged from previous version (fp16 packed output).
// Pass BC (NEW, fused): t=8..22 (bits 14..0). One 32768-pt chunk per block (h = bits 22..15),
//   data in registers (32 complex fp32/thread), 3 register-FFT phases over bits 14..10 / 9..5 / 4..0,
//   two fp32 LDS transposes (two 128KB half-phases each). Grid=256 -> 1 block/CU, all resident;
//   output lines are shared by blocks {h == c mod 32} which map to the same XCD under %8
//   round-robin, so the 8B-scattered stores merge in that XCD's L2.

__global__ __launch_bounds__(256) void fft_pass_a(const float* __restrict__ in,
                                                  const float2* __restrict__ wt,
                                                  uint4* __restrict__ outp)
{
    __shared__ float2 L[4096];   // [g*16 + c], 32 KB
    const int tid = threadIdx.x;
    const int l0  = blockIdx.x << 4;
    const int c   = tid & 15;
    const int qb  = tid >> 4;

    float2 pw1[4], pw2a[4], pw2b[4];
#pragma unroll
    for (int k = 0; k < 4; ++k) { pw1[k] = wt[0]; pw2a[k] = wt[0]; pw2b[k] = wt[1 << 21]; }

    // ---- load: real input, imag = 0 ----
    {
        const int c4 = tid & 3, gg = tid >> 2;
#pragma unroll
        for (int k = 0; k < 4; ++k) {
            const int g = gg + (k << 6);
            const float4 v = *reinterpret_cast<const float4*>(in + ((size_t)g << 15) + l0 + (c4 << 2));
            const int base = (g << 4) + (c4 << 2);
            L[base + 0] = make_float2(v.x, 0.f);
            L[base + 1] = make_float2(v.y, 0.f);
            L[base + 2] = make_float2(v.z, 0.f);
            L[base + 3] = make_float2(v.w, 0.f);
        }
    }
    __syncthreads();

#pragma unroll
    for (int rho = 0; rho < 4; ++rho) {
        const int s = rho << 1, H = 128 >> s, Q = H >> 1, lo = 6 - s;
        float2 nw1[4], nw2a[4], nw2b[4];
        if (rho < 3) {
            const int s2 = s + 2, lo2 = 6 - s2;
#pragma unroll
            for (int k = 0; k < 4; ++k) {
                const int qi = (qb << 2) + k;
                const int b  = ((qi >> lo2) << (lo2 + 2)) | (qi & ((1 << lo2) - 1));
                const int jl = (int)(__brev((unsigned)(b >> (8 - s2))) >> (32 - s2));
                const int e  = jl << (21 - s2);
                nw1[k] = wt[e << 1]; nw2a[k] = wt[e]; nw2b[k] = wt[e + (1 << 21)];
            }
        }
#pragma unroll
        for (int k = 0; k < 4; ++k) {
            const int qi = (qb << 2) + k;
            const int b  = ((qi >> lo) << (lo + 2)) | (qi & ((1 << lo) - 1));
            const int iA = (b << 4) + c;
            const float2 A  = L[iA];
            const float2 Bv = L[iA + (Q << 4)];
            const float2 Cv = L[iA + (H << 4)];
            const float2 Dv = L[iA + ((H + Q) << 4)];
            const float2 pC = cmul(pw1[k], Cv), pD = cmul(pw1[k], Dv);
            const float2 tA = cadd(A, pC),  tC = csub(A, pC);
            const float2 tB = cadd(Bv, pD), tD = csub(Bv, pD);
            const float2 p2 = cmul(pw2a[k], tB);
            const float2 p3 = cmul(pw2b[k], tD);
            L[iA]                  = cadd(tA, p2);
            L[iA + (Q << 4)]       = csub(tA, p2);
            L[iA + (H << 4)]       = cadd(tC, p3);
            L[iA + ((H + Q) << 4)] = csub(tC, p3);
        }
        __syncthreads();
        if (rho < 3) {
#pragma unroll
            for (int k = 0; k < 4; ++k) { pw1[k] = nw1[k]; pw2a[k] = nw2a[k]; pw2b[k] = nw2b[k]; }
        }
    }

    // ---- store packed fp16: 4 complex per uint4 ----
    {
        const int c4 = tid & 3, gg = tid >> 2;
#pragma unroll
        for (int k = 0; k < 4; ++k) {
            const int g  = gg + (k << 6);
            const int li = (g << 4) + (c4 << 2);
            uint4 v;
            v.x = pk(L[li]); v.y = pk(L[li + 1]); v.z = pk(L[li + 2]); v.w = pk(L[li + 3]);
            outp[((size_t)g << 13) + (l0 >> 2) + c4] = v;
        }
    }
}

// ---------------- fused stages 8..22 ----------------
// i = (h<<15) | (b<<10) | (u<<5) | v
// phase 1 regs=b (thread=(u,v)=tid), phase 2 regs=u (thread=(b,v)), phase 3 regs=v (thread=(b,u))
__global__ __launch_bounds__(1024) void fft_pass_bc(const unsigned* __restrict__ inp,
                                                    const float2* __restrict__ wt,
                                                    float2* __restrict__ out)
{
    extern __shared__ float2 T[];    // 16384 complex = 131072 B
    const int tid = threadIdx.x;
    const int h   = blockIdx.x;                    // identity map: siblings {h==c mod 32} share XCD (%8)
    const unsigned hrev = __brev((unsigned)h) >> 24;   // rev8(h)

    // ---- load: X[b] = buf[(h<<15) + (b<<10) + tid]  (coalesced 256B/wave-instr) ----
    float2 X[32];
    {
        const unsigned base = ((unsigned)h << 15) + (unsigned)tid;
#pragma unroll
        for (int b = 0; b < 32; ++b) X[b] = upk(inp[base + ((unsigned)b << 10)]);
    }

    // ---- phase 1: stages 8..12 over b ----
    // t=8+s1 flips b-bit beta=4-s1; j = (h<<s1)|(b>>(beta+1)); e = (rev_s1(c)<<8 | hrev) << (14-s1)
#pragma unroll
    for (int s1 = 0; s1 < 5; ++s1) {
        const int beta = 4 - s1, half = 1 << beta;
#pragma unroll
        for (int m = 0; m < 16; ++m) {
            const int lo = ((m >> beta) << (beta + 1)) | (m & (half - 1));
            const int hi = lo | half;
            const unsigned cr = crev((unsigned)(m >> beta), s1);
            const float2 w = wt[((cr << 8) | hrev) << (14 - s1)];
            const float2 p = cmul(w, X[hi]);
            X[hi] = csub(X[lo], p);
            X[lo] = cadd(X[lo], p);
        }
    }

    // ---- transpose 1 (fp32, two half-phases): (u,v) regs b  ->  (b,v) regs u ----
    float2 Y[32];
#pragma unroll
    for (int b = 0; b < 16; ++b) T[(b << 10) + tid] = X[b];
    __syncthreads();
    if (tid < 512) {
        const int sl = tid >> 5, v = tid & 31;
#pragma unroll
        for (int u = 0; u < 32; ++u) Y[u] = T[(sl << 10) + (u << 5) + v];
    }
    __syncthreads();
#pragma unroll
    for (int b = 16; b < 32; ++b) T[((b - 16) << 10) + tid] = X[b];
    __syncthreads();
    if (tid >= 512) {
        const int sl = (tid >> 5) - 16, v = tid & 31;
#pragma unroll
        for (int u = 0; u < 32; ++u) Y[u] = T[(sl << 10) + (u << 5) + v];
    }
    __syncthreads();

    // ---- phase 2: stages 13..17 over u ----
    const int b2 = tid >> 5, v2 = tid & 31;
    const unsigned brev5b = __brev((unsigned)b2) >> 27;
#pragma unroll
    for (int s2 = 0; s2 < 5; ++s2) {
        const int mu = 4 - s2, half = 1 << mu;
#pragma unroll
        for (int m = 0; m < 16; ++m) {
            const int lo = ((m >> mu) << (mu + 1)) | (m & (half - 1));
            const int hi = lo | half;
            const unsigned cr = crev((unsigned)(m >> mu), s2);
            const float2 w = wt[(((cr << 13) | (brev5b << 8) | hrev) << (9 - s2))];
            const float2 p = cmul(w, Y[hi]);
            Y[hi] = csub(Y[lo], p);
            Y[lo] = cadd(Y[lo], p);
        }
    }

    // ---- transpose 2 (fp32, two half-phases, rotation-swizzled): (b,v) regs u -> (b,u) regs v ----
    // element (b,u,v) at slice(b)*1024 + u*32 + ((u+v)&31)
    float2 Z[32];
    if (b2 < 16) {
#pragma unroll
        for (int u = 0; u < 32; ++u)
            T[(b2 << 10) + (u << 5) + ((u + v2) & 31)] = Y[u];
    }
    __syncthreads();
    if (b2 < 16) {
        const int u3 = tid & 31;
#pragma unroll
        for (int v = 0; v < 32; ++v)
            Z[v] = T[(b2 << 10) + (u3 << 5) + ((u3 + v) & 31)];
    }
    __syncthreads();
    if (b2 >= 16) {
#pragma unroll
        for (int u = 0; u < 32; ++u)
            T[((b2 - 16) << 10) + (u << 5) + ((u + v2) & 31)] = Y[u];
    }
    __syncthreads();
    if (b2 >= 16) {
        const int u3 = tid & 31;
#pragma unroll
        for (int v = 0; v < 32; ++v)
            Z[v] = T[((b2 - 16) << 10) + (u3 << 5) + ((u3 + v) & 31)];
    }

    // ---- phase 3: stages 18..22 over v ----
    const unsigned brev5u = __brev((unsigned)(tid & 31)) >> 27;
#pragma unroll
    for (int s3 = 0; s3 < 5; ++s3) {
        const int nu = 4 - s3, half = 1 << nu;
#pragma unroll
        for (int m = 0; m < 16; ++m) {
            const int lo = ((m >> nu) << (nu + 1)) | (m & (half - 1));
            const int hi = lo | half;
            const unsigned cr = crev((unsigned)(m >> nu), s3);
            const float2 w = wt[(((cr << 18) | (brev5u << 13) | (brev5b << 8) | hrev) << (4 - s3))];
            const float2 p = cmul(w, Z[hi]);
            Z[hi] = csub(Z[lo], p);
            Z[lo] = cadd(Z[lo], p);
        }
    }

    // ---- store fp32, full 23-bit reversal: o = rev5(v)<<18 | rev5(u)<<13 | rev5(b)<<8 | rev8(h) ----
    {
        const unsigned obase = (brev5u << 13) | (brev5b << 8) | hrev;
#pragma unroll
        for (int v = 0; v < 32; ++v)
            out[(crev((unsigned)v, 5) << 18) | obase] = Z[v];
    }
}

extern "C" void kernel_launch(void* const* d_in, const int* in_sizes, int n_in,
                              void* d_out, int out_size, void* d_ws, size_t ws_size,
                              hipStream_t stream)
{
    (void)in_sizes; (void)n_in; (void)out_size; (void)ws_size;
    const float*  in = (const float*)d_in[0];
    const float2* wt = (const float2*)d_in[1];
    float2* outc = (float2*)d_out;
    uint4*  buf1 = (uint4*)d_ws;                          // 32 MB packed fp16

    static bool attr_done = false;
    if (!attr_done) {
        (void)hipFuncSetAttribute(reinterpret_cast<const void*>(fft_pass_bc),
                                  hipFuncAttributeMaxDynamicSharedMemorySize, 131072);
        attr_done = true;
    }

    fft_pass_a<<<2048, 256, 0, stream>>>(in, wt, buf1);                        // stages 0..7
    fft_pass_bc<<<256, 1024, 131072, stream>>>((const unsigned*)buf1, wt, outc); // stages 8..22
}

// Round 3
// 198.392 us; speedup vs baseline: 1.6215x; 1.6215x over previous
//
#include <hip/hip_runtime.h>
#include <hip/hip_fp16.h>

__device__ __forceinline__ float2 cadd(float2 a, float2 b) { return make_float2(a.x + b.x, a.y + b.y); }
__device__ __forceinline__ float2 csub(float2 a, float2 b) { return make_float2(a.x - b.x, a.y - b.y); }
__device__ __forceinline__ float2 cmul(float2 w, float2 z) {
    return make_float2(w.x * z.x - w.y * z.y, w.x * z.y + w.y * z.x);
}
__device__ __forceinline__ unsigned pk(float2 z) {
    __half2 h = __floats2half2_rn(z.x, z.y);
    return *reinterpret_cast<unsigned*>(&h);
}
__device__ __forceinline__ float2 upk(unsigned u) {
    __half2 h = *reinterpret_cast<__half2*>(&u);
    return __half22float2(h);
}

__host__ __device__ constexpr unsigned crev(unsigned x, int bits) {
    unsigned r = 0;
    for (int k = 0; k < bits; ++k) r |= ((x >> k) & 1u) << (bits - 1 - k);
    return r;
}

// Butterfly network (DIF):
//   stage t (0..22): pairs (i, i + 2^(22-t)); z'[i] = z[i] + w*z[i+D]; z'[i+D] = z[i] - w*z[i+D]
//   w = weight[ bitrev_t(i >> (23-t)) * 2^(22-t) ];  final: out[rev23(i)] = z[i]
// Split: A: t=0..7 (bits 22..15, LDS tile)
//        B: t=8..12 (bits 14..10, radix-32 pure-register streaming, block-uniform twiddles)
//        C: t=13..22 (bits 9..0, 1024-pt FFTs; 8 bit-rev-selected chunks/block -> dense stores)

__global__ __launch_bounds__(256) void fft_pass_a(const float* __restrict__ in,
                                                  const float2* __restrict__ wt,
                                                  uint4* __restrict__ outp)
{
    __shared__ float2 L[4096];   // [g*16 + c], 32 KB
    const int tid = threadIdx.x;
    const int l0  = blockIdx.x << 4;
    const int c   = tid & 15;
    const int qb  = tid >> 4;

    float2 pw1[4], pw2a[4], pw2b[4];
#pragma unroll
    for (int k = 0; k < 4; ++k) { pw1[k] = wt[0]; pw2a[k] = wt[0]; pw2b[k] = wt[1 << 21]; }

    {
        const int c4 = tid & 3, gg = tid >> 2;
#pragma unroll
        for (int k = 0; k < 4; ++k) {
            const int g = gg + (k << 6);
            const float4 v = *reinterpret_cast<const float4*>(in + ((size_t)g << 15) + l0 + (c4 << 2));
            const int base = (g << 4) + (c4 << 2);
            L[base + 0] = make_float2(v.x, 0.f);
            L[base + 1] = make_float2(v.y, 0.f);
            L[base + 2] = make_float2(v.z, 0.f);
            L[base + 3] = make_float2(v.w, 0.f);
        }
    }
    __syncthreads();

#pragma unroll
    for (int rho = 0; rho < 4; ++rho) {
        const int s = rho << 1, H = 128 >> s, Q = H >> 1, lo = 6 - s;
        float2 nw1[4], nw2a[4], nw2b[4];
        if (rho < 3) {
            const int s2 = s + 2, lo2 = 6 - s2;
#pragma unroll
            for (int k = 0; k < 4; ++k) {
                const int qi = (qb << 2) + k;
                const int b  = ((qi >> lo2) << (lo2 + 2)) | (qi & ((1 << lo2) - 1));
                const int jl = (int)(__brev((unsigned)(b >> (8 - s2))) >> (32 - s2));
                const int e  = jl << (21 - s2);
                nw1[k] = wt[e << 1]; nw2a[k] = wt[e]; nw2b[k] = wt[e + (1 << 21)];
            }
        }
#pragma unroll
        for (int k = 0; k < 4; ++k) {
            const int qi = (qb << 2) + k;
            const int b  = ((qi >> lo) << (lo + 2)) | (qi & ((1 << lo) - 1));
            const int iA = (b << 4) + c;
            const float2 A  = L[iA];
            const float2 Bv = L[iA + (Q << 4)];
            const float2 Cv = L[iA + (H << 4)];
            const float2 Dv = L[iA + ((H + Q) << 4)];
            const float2 pC = cmul(pw1[k], Cv), pD = cmul(pw1[k], Dv);
            const float2 tA = cadd(A, pC),  tC = csub(A, pC);
            const float2 tB = cadd(Bv, pD), tD = csub(Bv, pD);
            const float2 p2 = cmul(pw2a[k], tB);
            const float2 p3 = cmul(pw2b[k], tD);
            L[iA]                  = cadd(tA, p2);
            L[iA + (Q << 4)]       = csub(tA, p2);
            L[iA + (H << 4)]       = cadd(tC, p3);
            L[iA + ((H + Q) << 4)] = csub(tC, p3);
        }
        __syncthreads();
        if (rho < 3) {
#pragma unroll
            for (int k = 0; k < 4; ++k) { pw1[k] = nw1[k]; pw2a[k] = nw2a[k]; pw2b[k] = nw2b[k]; }
        }
    }

    {
        const int c4 = tid & 3, gg = tid >> 2;
#pragma unroll
        for (int k = 0; k < 4; ++k) {
            const int g  = gg + (k << 6);
            const int li = (g << 4) + (c4 << 2);
            uint4 v;
            v.x = pk(L[li]); v.y = pk(L[li + 1]); v.z = pk(L[li + 2]); v.w = pk(L[li + 3]);
            outp[((size_t)g << 13) + (l0 >> 2) + c4] = v;
        }
    }
}

// ---- pass B: stages 8..12, radix-32 in registers, no LDS ----
// i = (h:8 | m:5 | low:10). Block: h = blk>>2 (uniform), low = (blk&3)<<8 | tid.
__global__ __launch_bounds__(256) void fft_pass_b(const unsigned* __restrict__ in,
                                                  const float2* __restrict__ wt,
                                                  unsigned* __restrict__ out)
{
    const int tid = threadIdx.x;
    const int h   = blockIdx.x >> 2;
    const int low = ((blockIdx.x & 3) << 8) | tid;
    const unsigned hrev = __brev((unsigned)h) >> 24;
    const unsigned base = ((unsigned)h << 15) | (unsigned)low;

    float2 X[32];
#pragma unroll
    for (int m = 0; m < 32; ++m) X[m] = upk(in[base + ((unsigned)m << 10)]);

#pragma unroll
    for (int s = 0; s < 5; ++s) {
        const int half = 1 << (4 - s);
#pragma unroll
        for (int j = 0; j < 16; ++j) {
            const int mh = j >> (4 - s);
            const int lo = (mh << (5 - s)) | (j & (half - 1));
            const int hi = lo | half;
            const unsigned cr = crev((unsigned)mh, s);
            const float2 w = wt[(((cr << 8) | hrev) << (14 - s))];
            const float2 p = cmul(w, X[hi]);
            X[hi] = csub(X[lo], p);
            X[lo] = cadd(X[lo], p);
        }
    }
#pragma unroll
    for (int m = 0; m < 32; ++m) out[base + ((unsigned)m << 10)] = pk(X[m]);
}

// ---- pass C: stages 13..22. 8 chunks (1024-pt each) per block, chunk H = rev13(h0*8+lm). ----
// LDS pitch 1026 float2 (b64 bank floor). Dense 64 B-line stores.
__global__ __launch_bounds__(512, 4) void fft_pass_c(const uint4* __restrict__ inp4,
                                                     const float2* __restrict__ wt,
                                                     float2* __restrict__ out)
{
    extern __shared__ float2 L[];            // 8 * 1026 * 8 B = 65,664 B
    const int tid = threadIdx.x;
    const int h0  = blockIdx.x;              // 0..1023
    const int lam = tid & 7;
    const int bq  = tid >> 3;                // 0..63
    const int R   = (h0 << 3) | lam;         // rev13(H) for this lane's chunk

    // load 8 chunks x 1024 packed fp16 (4 KB contiguous each); 4 uint4 per thread
    {
        const int f  = tid & 63;
        const int lm = tid >> 6;             // 0..7
        const unsigned H = __brev((unsigned)((h0 << 3) | lm)) >> 19;
        const size_t gb = ((size_t)H << 8);
#pragma unroll
        for (int k = 0; k < 4; ++k) {
            const uint4 v = inp4[gb + (k << 6) + f];
            const int base = lm * 1026 + (k << 8) + (f << 2);
            const float2 e0 = upk(v.x), e1 = upk(v.y), e2 = upk(v.z), e3 = upk(v.w);
            *reinterpret_cast<float4*>(&L[base])     = make_float4(e0.x, e0.y, e1.x, e1.y);
            *reinterpret_cast<float4*>(&L[base + 2]) = make_float4(e2.x, e2.y, e3.x, e3.y);
        }
    }
    __syncthreads();

    // rounds rho=0..3: stages (13,14),(15,16),(17,18),(19,20)
#pragma unroll
    for (int rho = 0; rho < 4; ++rho) {
        const int sh = 8 - (rho << 1);       // 8,6,4,2
        const int Q  = 1 << sh;
        const int H2 = Q << 1;
#pragma unroll
        for (int k = 0; k < 4; ++k) {
            const int qi = (k << 6) | bq;    // 0..255
            const int x  = ((qi >> sh) << (sh + 2)) | (qi & (Q - 1));
            const int a  = x >> (sh + 2);    // 2*rho bits
            const unsigned xr = rho ? (__brev((unsigned)a) >> (32 - (rho << 1))) : 0u;
            const int e  = (int)((((xr << 13) | (unsigned)R)) << sh);
            const float2 w1  = wt[e << 1];
            const float2 w2a = wt[e];
            const float2 w2b = wt[e + (1 << 21)];
            const int iA = lam * 1026 + x;
            const float2 A  = L[iA];
            const float2 Bv = L[iA + Q];
            const float2 Cv = L[iA + H2];
            const float2 Dv = L[iA + H2 + Q];
            const float2 pC = cmul(w1, Cv), pD = cmul(w1, Dv);
            const float2 tA = cadd(A, pC),  tC = csub(A, pC);
            const float2 tB = cadd(Bv, pD), tD = csub(Bv, pD);
            const float2 p2 = cmul(w2a, tB);
            const float2 p3 = cmul(w2b, tD);
            L[iA]           = cadd(tA, p2);
            L[iA + Q]       = csub(tA, p2);
            L[iA + H2]      = cadd(tC, p3);
            L[iA + H2 + Q]  = csub(tC, p3);
        }
        __syncthreads();
    }

    // round rho=4: stages (21,22), legs adjacent -> float4 LDS I/O
    {
#pragma unroll
        for (int k = 0; k < 4; ++k) {
            const int qi = (k << 6) | bq;            // 0..255
            const int x  = qi << 2;
            const unsigned xr = __brev((unsigned)qi) >> 24;   // rev8
            const int e  = (int)((xr << 13) | (unsigned)R);
            const float2 w1  = wt[e << 1];
            const float2 w2a = wt[e];
            const float2 w2b = wt[e + (1 << 21)];
            const int iA = lam * 1026 + x;
            const float4 f0 = *reinterpret_cast<const float4*>(&L[iA]);
            const float4 f1 = *reinterpret_cast<const float4*>(&L[iA + 2]);
            const float2 A  = make_float2(f0.x, f0.y);
            const float2 Bv = make_float2(f0.z, f0.w);
            const float2 Cv = make_float2(f1.x, f1.y);
            const float2 Dv = make_float2(f1.z, f1.w);
            const float2 pC = cmul(w1, Cv), pD = cmul(w1, Dv);
            const float2 tA = cadd(A, pC),  tC = csub(A, pC);
            const float2 tB = cadd(Bv, pD), tD = csub(Bv, pD);
            const float2 p2 = cmul(w2a, tB);
            const float2 p3 = cmul(w2b, tD);
            const float2 rA = cadd(tA, p2), rB = csub(tA, p2);
            const float2 rC = cadd(tC, p3), rD = csub(tC, p3);
            *reinterpret_cast<float4*>(&L[iA])     = make_float4(rA.x, rA.y, rB.x, rB.y);
            *reinterpret_cast<float4*>(&L[iA + 2]) = make_float4(rC.x, rC.y, rD.x, rD.y);
        }
    }
    __syncthreads();

    // store: out[rev10(x)<<13 | h0<<3 | lm] — 8 consecutive lm = one 64 B line
    {
        const int l2 = (tid & 3) << 1;       // 0,2,4,6
        const int xb = tid >> 2;             // 0..127
#pragma unroll
        for (int k = 0; k < 8; ++k) {
            const int x = (k << 7) | xb;
            const float2 a0 = L[l2 * 1026 + x];
            const float2 a1 = L[(l2 + 1) * 1026 + x];
            const size_t o = ((size_t)(__brev((unsigned)x) >> 22) << 13)
                           | (unsigned)((h0 << 3) | l2);
            *reinterpret_cast<float4*>(out + o) = make_float4(a0.x, a0.y, a1.x, a1.y);
        }
    }
}

extern "C" void kernel_launch(void* const* d_in, const int* in_sizes, int n_in,
                              void* d_out, int out_size, void* d_ws, size_t ws_size,
                              hipStream_t stream)
{
    (void)in_sizes; (void)n_in; (void)out_size; (void)ws_size;
    const float*  in = (const float*)d_in[0];
    const float2* wt = (const float2*)d_in[1];
    float2* outc = (float2*)d_out;
    uint4*  buf1 = (uint4*)d_ws;                          // 32 MB packed fp16
    unsigned* buf2 = (unsigned*)((char*)d_ws + (32u << 20)); // 32 MB packed fp16

    static bool attr_done = false;
    if (!attr_done) {
        (void)hipFuncSetAttribute(reinterpret_cast<const void*>(fft_pass_c),
                                  hipFuncAttributeMaxDynamicSharedMemorySize, 8 * 1026 * 8);
        attr_done = true;
    }

    fft_pass_a<<<2048, 256, 0, stream>>>(in, wt, buf1);                            // t=0..7
    fft_pass_b<<<1024, 256, 0, stream>>>((const unsigned*)buf1, wt, buf2);         // t=8..12
    fft_pass_c<<<1024, 512, 8 * 1026 * 8, stream>>>((const uint4*)buf2, wt, outc); // t=13..22
}